// Round 7
// baseline (688.175 us; speedup 1.0000x reference)
//
#include <hip/hip_runtime.h>
#include <math.h>

typedef unsigned short u16;
typedef __bf16 bf16;
typedef bf16 bf16x8 __attribute__((ext_vector_type(8)));
typedef float f32x4 __attribute__((ext_vector_type(4)));

__device__ __forceinline__ float b2f(u16 u) {
    union { unsigned int i; float f; } w;
    w.i = ((unsigned int)u) << 16;
    return w.f;
}
// native RNE f32->bf16 (one v_cvt instead of 4 integer ops)
__device__ __forceinline__ u16 f2b(float f) {
    union { bf16 h; u16 u; } cv;
    cv.h = (bf16)f;
    return cv.u;
}
__device__ __forceinline__ void gload16(const void* g, void* l) {
    __builtin_amdgcn_global_load_lds(
        (const __attribute__((address_space(1))) unsigned int*)g,
        (__attribute__((address_space(3))) unsigned int*)l, 16, 0, 0);
}

// ---------------------------------------------------------- input dtype sniff
__global__ __launch_bounds__(256)
void sniff_kernel(const u16* __restrict__ w, int* __restrict__ flag) {
    __shared__ int s;
    if (threadIdx.x == 0) s = 0;
    __syncthreads();
    int big = 0;
    for (int i = threadIdx.x; i < 2048; i += 256) {
        float v = fabsf(b2f(w[2 * i]));
        if (!(v < 1e6f)) big = 1;
    }
    if (big) atomicOr(&s, 1);
    __syncthreads();
    if (threadIdx.x == 0) flag[0] = s;
}

// --------------------- 4x square weight transpose W[1024][1024]->WT (one launch)
__global__ __launch_bounds__(256)
void transpose_w4_kernel(const void* __restrict__ W0, const void* __restrict__ W1,
                         const void* __restrict__ W2, const void* __restrict__ W3,
                         const int* __restrict__ flag, u16* __restrict__ oQKV,
                         u16* __restrict__ oA) {
    __shared__ float T[32][33];
    const int z = blockIdx.z;
    const void* W = z == 0 ? W0 : (z == 1 ? W1 : (z == 2 ? W2 : W3));
    u16* out = z == 3 ? oA : (oQKV + (size_t)z * 1024 * 1024);
    const float scale = z == 0 ? (1.f / 64.f) : 1.f;
    const int tx = threadIdx.x & 31, ty = threadIdx.x >> 5;   // 32 x 8
    const int kt = blockIdx.y * 32, nt = blockIdx.x * 32;
    const int isf = flag[0];
#pragma unroll
    for (int r = 0; r < 4; ++r) {
        int k = kt + ty + r * 8;
        float v = isf ? ((const float*)W)[(size_t)k * 1024 + nt + tx]
                      : b2f(((const u16*)W)[(size_t)k * 1024 + nt + tx]);
        T[ty + r * 8][tx] = v;
    }
    __syncthreads();
#pragma unroll
    for (int r = 0; r < 4; ++r) {
        int n = nt + ty + r * 8;
        out[(size_t)n * 1024 + kt + tx] = f2b(T[tx][ty + r * 8] * scale);
    }
}

// ------------------------------------------- generic transpose (fc1/fc2)
__global__ __launch_bounds__(256)
void transpose_w_kernel(const void* __restrict__ W, const int* __restrict__ flag,
                        int K, int N, u16* __restrict__ out) {
    __shared__ float T[32][33];
    const int tx = threadIdx.x & 31, ty = threadIdx.x >> 5;
    const int kt = blockIdx.y * 32, nt = blockIdx.x * 32;
    const int isf = flag[0];
#pragma unroll
    for (int r = 0; r < 4; ++r) {
        int k = kt + ty + r * 8;
        float v = isf ? ((const float*)W)[(size_t)k * N + nt + tx]
                      : b2f(((const u16*)W)[(size_t)k * N + nt + tx]);
        T[ty + r * 8][tx] = v;
    }
    __syncthreads();
#pragma unroll
    for (int r = 0; r < 4; ++r) {
        int n = nt + ty + r * 8;
        out[(size_t)n * K + kt + tx] = f2b(T[tx][ty + r * 8]);
    }
}

// ------------------------------------------- concat qkv bias (q scaled 1/64)
__global__ __launch_bounds__(256)
void biasqkv_kernel(const void* __restrict__ bq, const void* __restrict__ bk,
                    const void* __restrict__ bv, const int* __restrict__ flag,
                    float* __restrict__ out) {
    int i = blockIdx.x * 256 + threadIdx.x;
    if (i >= 3072) return;
    const int isf = flag[0];
    const void* src = i < 1024 ? bq : (i < 2048 ? bk : bv);
    int j = i & 1023;
    float v = isf ? ((const float*)src)[j] : b2f(((const u16*)src)[j]);
    if (i < 1024) v *= (1.f / 64.f);
    out[i] = v;
}

// ---------------------------------------------------------------- silu(c)
__global__ __launch_bounds__(256)
void silu_kernel(const void* __restrict__ c, const int* __restrict__ flag,
                 float* __restrict__ cactf, float* __restrict__ out_cact) {
    int i = blockIdx.x * 256 + threadIdx.x;
    if (i < 8 * 1024) {
        float v = flag[0] ? ((const float*)c)[i] : b2f(((const u16*)c)[i]);
        float s = v / (1.f + expf(-v));
        cactf[i] = s;
        out_cact[i] = s;
    }
}

// ---------------------------- cmod stage 1: partial[ks][b][j] over 128 k's
__global__ __launch_bounds__(256)
void cmod1_kernel(const float* __restrict__ cactf, const void* __restrict__ w_mod,
                  const int* __restrict__ flag, float* __restrict__ partial) {
    __shared__ float sca[8][128];
    const int tid = threadIdx.x;
    const int ks = blockIdx.y;
    if (tid < 128) {
#pragma unroll
        for (int b = 0; b < 8; ++b) sca[b][tid] = cactf[b * 1024 + ks * 128 + tid];
    }
    __syncthreads();
    const int j = blockIdx.x * 256 + tid;
    const int isf = flag[0];
    float acc[8] = {};
    if (isf) {
        const float* wf = (const float*)w_mod + (size_t)(ks * 128) * 6144 + j;
        for (int k = 0; k < 128; ++k) {
            float wv = wf[(size_t)k * 6144];
#pragma unroll
            for (int b = 0; b < 8; ++b) acc[b] = fmaf(sca[b][k], wv, acc[b]);
        }
    } else {
        const u16* wb = (const u16*)w_mod + (size_t)(ks * 128) * 6144 + j;
        for (int k = 0; k < 128; ++k) {
            float wv = b2f(wb[(size_t)k * 6144]);
#pragma unroll
            for (int b = 0; b < 8; ++b) acc[b] = fmaf(sca[b][k], wv, acc[b]);
        }
    }
#pragma unroll
    for (int b = 0; b < 8; ++b) partial[(ks * 8 + b) * 6144 + j] = acc[b];
}

// ---------------------------- cmod stage 2: reduce + bias + outputs
__global__ __launch_bounds__(256)
void cmod2_kernel(const float* __restrict__ partial, const void* __restrict__ b_mod,
                  const int* __restrict__ flag, float* __restrict__ cmodf,
                  float* __restrict__ out_cmod, float* __restrict__ out_shift,
                  float* __restrict__ out_scale) {
    const int j = blockIdx.x * 256 + threadIdx.x;
    const int isf = flag[0];
    float bm = isf ? ((const float*)b_mod)[j] : b2f(((const u16*)b_mod)[j]);
#pragma unroll
    for (int b = 0; b < 8; ++b) {
        float acc = bm;
#pragma unroll
        for (int ks = 0; ks < 8; ++ks) acc += partial[(ks * 8 + b) * 6144 + j];
        cmodf[b * 6144 + j] = acc;
        out_cmod[b * 6144 + j] = acc;
        if (j < 1024) out_shift[b * 1024 + j] = acc;
        else if (j < 2048) out_scale[b * 1024 + (j - 1024)] = acc;
    }
}

// -------------------------------------------------- LayerNorm + modulate
__global__ __launch_bounds__(256)
void ln_mod_kernel(const void* __restrict__ xin, const int* __restrict__ flag,
                   int dtype, const float* __restrict__ cmodf,
                   int shift_off, int scale_off, float* __restrict__ out_norm,
                   float* __restrict__ out_mod, u16* __restrict__ ws_mod) {
    const int row = blockIdx.x;
    const int tid = threadIdx.x;
    const int bidx = row >> 10;
    const int isf = (dtype == 2) ? flag[0] : dtype;
    const size_t base = (size_t)row * 1024 + tid * 4;
    float v[4];
    if (isf) {
        float4 f = *reinterpret_cast<const float4*>((const float*)xin + base);
        v[0] = f.x; v[1] = f.y; v[2] = f.z; v[3] = f.w;
    } else {
        ushort4 u = *reinterpret_cast<const ushort4*>((const u16*)xin + base);
        v[0] = b2f(u.x); v[1] = b2f(u.y); v[2] = b2f(u.z); v[3] = b2f(u.w);
    }
    float s = v[0] + v[1] + v[2] + v[3];
#pragma unroll
    for (int o = 32; o; o >>= 1) s += __shfl_xor(s, o, 64);
    __shared__ float red1[4], red2[4];
    const int lane = tid & 63, wv = tid >> 6;
    if (lane == 0) red1[wv] = s;
    __syncthreads();
    float mean = (red1[0] + red1[1] + red1[2] + red1[3]) * 0.0009765625f;
    float d0 = v[0] - mean, d1 = v[1] - mean, d2 = v[2] - mean, d3 = v[3] - mean;
    float sq = d0 * d0 + d1 * d1 + d2 * d2 + d3 * d3;
#pragma unroll
    for (int o = 32; o; o >>= 1) sq += __shfl_xor(sq, o, 64);
    if (lane == 0) red2[wv] = sq;
    __syncthreads();
    float var = (red2[0] + red2[1] + red2[2] + red2[3]) * 0.0009765625f;
    float rs = rsqrtf(var + 1e-6f);
    float xn[4] = {d0 * rs, d1 * rs, d2 * rs, d3 * rs};
    const int d = tid * 4;
    const float* cb = cmodf + bidx * 6144;
    float4 fn = {xn[0], xn[1], xn[2], xn[3]};
    float4 fm;
    fm.x = xn[0] * (1.f + cb[scale_off + d + 0]) + cb[shift_off + d + 0];
    fm.y = xn[1] * (1.f + cb[scale_off + d + 1]) + cb[shift_off + d + 1];
    fm.z = xn[2] * (1.f + cb[scale_off + d + 2]) + cb[shift_off + d + 2];
    fm.w = xn[3] * (1.f + cb[scale_off + d + 3]) + cb[shift_off + d + 3];
    if (out_norm) *reinterpret_cast<float4*>(out_norm + base) = fn;
    if (out_mod)  *reinterpret_cast<float4*>(out_mod + base)  = fm;
    if (ws_mod) {
        ushort4 um = {f2b(fm.x), f2b(fm.y), f2b(fm.z), f2b(fm.w)};
        *reinterpret_cast<ushort4*>(ws_mod + base) = um;
    }
}

// ------------------------------------------------------------ MFMA GEMM (m97)
// MODE 0: qkv: Q,K parts -> Cb; V part -> VTg[b][h][dh][s] (transposed store)
// MODE 1: x1b = bf16(f(Xres) + gate_msa * C)
// MODE 2: Cb = bf16(gelu_exact(C))
// MODE 3: outf = f(x1b) + gate_mlp * C
// v3: XCD-aware chunked block swizzle (T1).
// v4: BK=64 (halves barrier/drain events per K-element).
// v5: T2 XOR swizzle, both-sides (rule #21).
template <int MODE>
__global__ __launch_bounds__(256, 2)
void gemm_kernel(const u16* __restrict__ A, const u16* __restrict__ BT,
                 const void* __restrict__ bias, const float* __restrict__ bias32,
                 const int* __restrict__ flag, int M, int N, int K,
                 u16* __restrict__ Cb, const void* __restrict__ Xres,
                 const float* __restrict__ cmodf, int gate_off,
                 u16* __restrict__ x1b, float* __restrict__ outf,
                 u16* __restrict__ VTg) {
    __shared__ __align__(16) u16 Al[128 * 64];
    __shared__ __align__(16) u16 Bl[128 * 64];
    const int tid = threadIdx.x, lane = tid & 63, w = tid >> 6;
    const int nwg = gridDim.x * gridDim.y;
    const int bid = blockIdx.y * gridDim.x + blockIdx.x;
    const int swz = (bid & 7) * (nwg >> 3) + (bid >> 3);
    const int m0 = (swz / gridDim.x) * 128, n0 = (swz % gridDim.x) * 128;
    const int wr = (w & 1) * 64, wc = (w >> 1) * 64;
    const int l15 = lane & 15, quad = lane >> 4;
    const int srow = lane >> 3;                              // 0..7 within chunk
    const int sslot = ((lane & 7) ^ srow) * 8;               // pre-swizzled src slot (u16)
    const int m7 = l15 & 7;
    const int s0 = (quad ^ m7) * 8;                          // kk=0 read slot (u16)
    const int s1 = ((4 + quad) ^ m7) * 8;                    // kk=1 read slot (u16)
    f32x4 acc[4][4] = {};
    for (int k0 = 0; k0 < K; k0 += 64) {
        __syncthreads();
#pragma unroll
        for (int c = 0; c < 4; ++c) {
            const int chunk = w * 4 + c;              // 16 chunks of 8 rows
            const int row = chunk * 8 + srow;
            gload16(A + (size_t)(m0 + row) * K + k0 + sslot, &Al[chunk * 512]);
            gload16(BT + (size_t)(n0 + row) * K + k0 + sslot, &Bl[chunk * 512]);
        }
        __syncthreads();
#pragma unroll
        for (int kk = 0; kk < 2; ++kk) {
            const int sk = kk ? s1 : s0;
            bf16x8 afr[4], bfr[4];
#pragma unroll
            for (int i = 0; i < 4; ++i)
                afr[i] = *(const bf16x8*)&Al[(wr + i * 16 + l15) * 64 + sk];
#pragma unroll
            for (int j = 0; j < 4; ++j)
                bfr[j] = *(const bf16x8*)&Bl[(wc + j * 16 + l15) * 64 + sk];
#pragma unroll
            for (int i = 0; i < 4; ++i)
#pragma unroll
                for (int j = 0; j < 4; ++j)
                    acc[i][j] = __builtin_amdgcn_mfma_f32_16x16x32_bf16(
                        afr[i], bfr[j], acc[i][j], 0, 0, 0);
        }
    }
    const int isf = flag[0];
    const int rbase = (lane >> 4) << 2;
#pragma unroll
    for (int i = 0; i < 4; ++i) {
#pragma unroll
        for (int j = 0; j < 4; ++j) {
            const int colbase = n0 + wc + j * 16;
            const int col = colbase + l15;
            float bv;
            if (MODE == 0) bv = bias32[col];
            else bv = isf ? ((const float*)bias)[col] : b2f(((const u16*)bias)[col]);
#pragma unroll
            for (int r = 0; r < 4; ++r) {
                const int m = m0 + wr + i * 16 + rbase + r;
                float t = acc[i][j][r] + bv;
                const size_t idx = (size_t)m * N + col;
                if (MODE == 0) {
                    if (colbase >= 2048) {   // V part: store transposed
                        const int hh = (col - 2048) >> 6, dh = (col - 2048) & 63;
                        const int bb = m >> 10, ss = m & 1023;
                        VTg[(((size_t)bb * 16 + hh) * 64 + dh) * 1024 + ss] = f2b(t);
                    } else {
                        Cb[idx] = f2b(t);
                    }
                } else if (MODE == 1) {
                    const int bb = m >> 10;
                    float g = cmodf[bb * 6144 + gate_off + col];
                    float xr = isf ? ((const float*)Xres)[idx]
                                   : b2f(((const u16*)Xres)[idx]);
                    x1b[idx] = f2b(xr + g * t);
                } else if (MODE == 2) {
                    float gl = 0.5f * t * (1.f + erff(t * 0.70710678118654752f));
                    Cb[idx] = f2b(gl);
                } else {
                    const int bb = m >> 10;
                    float g = cmodf[bb * 6144 + gate_off + col];
                    outf[idx] = b2f(x1b[idx]) + g * t;
                }
            }
        }
    }
}

// --------------------------------------------- fused flash attention (64-row Q)
// QKV[8192][3072] (Q+0, K+1024; V region unused), VT[b][h][64][1024].
// v2: qS dropped (Q direct to regs); async-STAGE split (T14); setprio (T5).
// v3: XCD-aware chunked swizzle (T1) — each XCD owns one batch b.
// v5: KVBLK back to 128 (v4's 64 regressed: TLP was not the bottleneck);
//     + T13 defer-max: skip alpha-exp/m_i-update/accO-rescale when per-tile
//     max growth <= 8 (wave-uniform __all branch; P bounded by e^8, exact
//     math when not deferred; first tile always takes full path);
//     + native f2b (v_cvt) on the hot P->LDS path.
__global__ __launch_bounds__(256, 2)
void attn_kernel(const u16* __restrict__ QKV, const u16* __restrict__ VT,
                 u16* __restrict__ Y) {
    __shared__ __align__(16) u16 kS[128 * 72];
    __shared__ __align__(16) u16 vS[64 * 132];   // [dh][key]
    __shared__ __align__(16) u16 pS[64 * 132];   // [q][key]
    const int tid = threadIdx.x, lane = tid & 63, w = tid >> 6;
    const int l15 = lane & 15, quad = lane >> 4;
    const int kq = quad * 8, rbase = quad * 4;
    // swizzle: nwg = 16*16*8 = 2048; chunk 256 per XCD = exactly one batch b
    const int bid = blockIdx.x + 16 * (blockIdx.y + 16 * blockIdx.z);
    const int swz = (bid & 7) * 256 + (bid >> 3);
    const int qt = swz & 15, h = (swz >> 4) & 15, b = swz >> 8;
    const int s0 = qt * 64;
    const size_t rowbase = (size_t)b * 1024;
    const int hq = h * 64, hk = 1024 + h * 64;
    const u16* vtg = VT + ((size_t)b * 16 + h) * 64 * 1024;
    // Q fragments straight from global (one-time, 32B/thread)
    bf16x8 qa[2];
#pragma unroll
    for (int ks = 0; ks < 2; ++ks)
        qa[ks] = *(const bf16x8*)(QKV + (rowbase + s0 + w * 16 + l15) * 3072 +
                                  hq + ks * 32 + kq);
    // prefetch K/V tile 0 into registers
    bf16x8 kreg[4], vreg[4];
#pragma unroll
    for (int it = 0; it < 4; ++it) {
        int idx = it * 256 + tid;
        int r = idx >> 3, ch = idx & 7;
        kreg[it] = *(const bf16x8*)(QKV + (rowbase + r) * 3072 + hk + ch * 8);
        int dh = idx >> 4, kc = idx & 15;
        vreg[it] = *(const bf16x8*)(vtg + (size_t)dh * 1024 + kc * 8);
    }
    f32x4 accO[4] = {};
    float m_i[4], l_i[4];
#pragma unroll
    for (int r = 0; r < 4; ++r) { m_i[r] = -3e38f; l_i[r] = 0.f; }
    for (int kt = 0; kt < 8; ++kt) {
        __syncthreads();                     // prev tile LDS fully consumed
        // write prefetched tile regs -> LDS
#pragma unroll
        for (int it = 0; it < 4; ++it) {
            int idx = it * 256 + tid;
            int r = idx >> 3, ch = idx & 7;
            *(bf16x8*)&kS[r * 72 + ch * 8] = kreg[it];
            int dh = idx >> 4, kc = idx & 15;
            *(bf16x8*)&vS[dh * 132 + kc * 8] = vreg[it];
        }
        // issue next tile's global loads now; latency hides under compute below
        if (kt < 7) {
#pragma unroll
            for (int it = 0; it < 4; ++it) {
                int idx = it * 256 + tid;
                int r = idx >> 3, ch = idx & 7;
                kreg[it] = *(const bf16x8*)(QKV + (rowbase + (kt + 1) * 128 + r) * 3072 +
                                            hk + ch * 8);
                int dh = idx >> 4, kc = idx & 15;
                vreg[it] = *(const bf16x8*)(vtg + (size_t)dh * 1024 +
                                            (kt + 1) * 128 + kc * 8);
            }
        }
        __syncthreads();
        // S = Q K^T
        f32x4 s[8];
        __builtin_amdgcn_s_setprio(1);
#pragma unroll
        for (int nt = 0; nt < 8; ++nt) {
            f32x4 a = {};
#pragma unroll
            for (int ks = 0; ks < 2; ++ks) {
                bf16x8 kb = *(const bf16x8*)&kS[(nt * 16 + l15) * 72 + ks * 32 + kq];
                a = __builtin_amdgcn_mfma_f32_16x16x32_bf16(qa[ks], kb, a, 0, 0, 0);
            }
            s[nt] = a;
        }
        __builtin_amdgcn_s_setprio(0);
        // tile max per row (cross-lane over the 16-lane row group)
        float mxr[4];
#pragma unroll
        for (int r = 0; r < 4; ++r) {
            float mx = fmaxf(fmaxf(fmaxf(s[0][r], s[1][r]), fmaxf(s[2][r], s[3][r])),
                             fmaxf(fmaxf(s[4][r], s[5][r]), fmaxf(s[6][r], s[7][r])));
            mx = fmaxf(mx, __shfl_xor(mx, 1));
            mx = fmaxf(mx, __shfl_xor(mx, 2));
            mx = fmaxf(mx, __shfl_xor(mx, 4));
            mx = fmaxf(mx, __shfl_xor(mx, 8));
            mxr[r] = mx;
        }
        // T13 defer-max: if no row grew its max by >8, keep m_i (alpha=1)
        const int defer = __all((mxr[0] - m_i[0] <= 8.f) &&
                                (mxr[1] - m_i[1] <= 8.f) &&
                                (mxr[2] - m_i[2] <= 8.f) &&
                                (mxr[3] - m_i[3] <= 8.f));
        float alpha[4];
        if (defer) {
#pragma unroll
            for (int r = 0; r < 4; ++r) {
                float rs = 0.f;
#pragma unroll
                for (int nt = 0; nt < 8; ++nt) {
                    float p = __expf(s[nt][r] - m_i[r]);
                    s[nt][r] = p;
                    rs += p;
                }
                rs += __shfl_xor(rs, 1);
                rs += __shfl_xor(rs, 2);
                rs += __shfl_xor(rs, 4);
                rs += __shfl_xor(rs, 8);
                l_i[r] += rs;
            }
        } else {
#pragma unroll
            for (int r = 0; r < 4; ++r) {
                float mn = fmaxf(m_i[r], mxr[r]);
                alpha[r] = __expf(m_i[r] - mn);
                m_i[r] = mn;
                float rs = 0.f;
#pragma unroll
                for (int nt = 0; nt < 8; ++nt) {
                    float p = __expf(s[nt][r] - mn);
                    s[nt][r] = p;
                    rs += p;
                }
                rs += __shfl_xor(rs, 1);
                rs += __shfl_xor(rs, 2);
                rs += __shfl_xor(rs, 4);
                rs += __shfl_xor(rs, 8);
                l_i[r] = l_i[r] * alpha[r] + rs;
            }
        }
        // P -> LDS, direct scalar u16 stores (2-way banks with 132 stride)
#pragma unroll
        for (int nt = 0; nt < 8; ++nt)
#pragma unroll
            for (int r = 0; r < 4; ++r)
                pS[(w * 16 + rbase + r) * 132 + nt * 16 + l15] = f2b(s[nt][r]);
        __syncthreads();
        if (!defer) {
#pragma unroll
            for (int dt = 0; dt < 4; ++dt)
#pragma unroll
                for (int r = 0; r < 4; ++r) accO[dt][r] *= alpha[r];
        }
        bf16x8 pa[4];
#pragma unroll
        for (int ks = 0; ks < 4; ++ks)
            pa[ks] = *(const bf16x8*)&pS[(w * 16 + l15) * 132 + ks * 32 + kq];
        __builtin_amdgcn_s_setprio(1);
#pragma unroll
        for (int dt = 0; dt < 4; ++dt) {
#pragma unroll
            for (int ks = 0; ks < 4; ++ks) {
                bf16x8 vb = *(const bf16x8*)&vS[(dt * 16 + l15) * 132 + ks * 32 + kq];
                accO[dt] = __builtin_amdgcn_mfma_f32_16x16x32_bf16(pa[ks], vb, accO[dt], 0, 0, 0);
            }
        }
        __builtin_amdgcn_s_setprio(0);
    }
#pragma unroll
    for (int dt = 0; dt < 4; ++dt)
#pragma unroll
        for (int r = 0; r < 4; ++r) {
            float o = accO[dt][r] / l_i[r];
            Y[(rowbase + s0 + w * 16 + rbase + r) * 1024 + h * 64 + dt * 16 + l15] = f2b(o);
        }
}

// ----------------------------------------------------------------- launch
extern "C" void kernel_launch(void* const* d_in, const int* in_sizes, int n_in,
                              void* d_out, int out_size, void* d_ws, size_t ws_size,
                              hipStream_t stream) {
    const void* x      = d_in[0];
    const void* c      = d_in[1];
    const void* w_mod  = d_in[2];
    const void* b_mod  = d_in[3];
    const void* w_q    = d_in[4];
    const void* b_q    = d_in[5];
    const void* w_k    = d_in[6];
    const void* b_k    = d_in[7];
    const void* w_v    = d_in[8];
    const void* b_v    = d_in[9];
    const void* w_attn = d_in[10];
    const void* b_attn = d_in[11];
    const void* w_fc1  = d_in[12];
    const void* b_fc1  = d_in[13];
    const void* w_fc2  = d_in[14];
    const void* b_fc2  = d_in[15];

    float* out = (float*)d_out;
    float* out_xout  = out;
    float* out_norm  = out + 8388608;
    float* out_mod   = out + 16777216;
    float* out_shift = out + 25165824;
    float* out_scale = out + 25174016;
    float* out_cmod  = out + 25182208;
    float* out_cact  = out + 25231360;

    char* ws = (char*)d_ws;
    float* cactf   = (float*)(ws + 0);
    float* cmodf   = (float*)(ws + 32768);
    int*   flag    = (int*)(ws + 229376);
    float* bqkv    = (float*)(ws + 230400);
    float* partial = (float*)(ws + 262144);      // 1.57 MB
    u16* wqkvT = (u16*)(ws + 2097152);           // 6 MB
    u16* waT   = (u16*)(ws + 8388608);           // 2 MB
    u16* wf1T  = (u16*)(ws + 10485760);          // 8 MB
    u16* wf2T  = (u16*)(ws + 18874368);          // 8 MB  (end 27262976)
    u16* xmod  = (u16*)(ws + 27262976);          // 16 MB
    u16* yw    = xmod;                           // alias: xmod dead after qkv GEMM
    u16* qkv   = (u16*)(ws + 44040192);          // 48 MB (V third unused)
    u16* xmod2 = qkv;                            // alias: qkv dead after attn
    u16* vtg   = (u16*)(ws + 94371840);          // 16 MB
    u16* hw    = (u16*)(ws + 60817408);          // 64 MB, overlays dead qkv-tail+vtg
    u16* x1b   = (u16*)(ws + 127926272);         // 16 MB (end ~138 MiB)

    sniff_kernel<<<1, 256, 0, stream>>>((const u16*)w_q, flag);
    transpose_w4_kernel<<<dim3(32, 32, 4), 256, 0, stream>>>(w_q, w_k, w_v, w_attn,
        flag, wqkvT, waT);
    transpose_w_kernel<<<dim3(128, 32), 256, 0, stream>>>(w_fc1, flag, 1024, 4096, wf1T);
    transpose_w_kernel<<<dim3(32, 128), 256, 0, stream>>>(w_fc2, flag, 4096, 1024, wf2T);
    biasqkv_kernel<<<12, 256, 0, stream>>>(b_q, b_k, b_v, flag, bqkv);

    silu_kernel<<<32, 256, 0, stream>>>(c, flag, cactf, out_cact);
    cmod1_kernel<<<dim3(24, 8), 256, 0, stream>>>(cactf, w_mod, flag, partial);
    cmod2_kernel<<<24, 256, 0, stream>>>(partial, b_mod, flag, cmodf,
                                         out_cmod, out_shift, out_scale);
    ln_mod_kernel<<<8192, 256, 0, stream>>>(x, flag, 2, cmodf, 0, 1024,
                                            out_norm, out_mod, xmod);
    gemm_kernel<0><<<dim3(24, 64), 256, 0, stream>>>(xmod, wqkvT, nullptr, bqkv,
        flag, 8192, 3072, 1024, qkv, nullptr, nullptr, 0, nullptr, nullptr, vtg);
    attn_kernel<<<dim3(16, 16, 8), 256, 0, stream>>>(qkv, vtg, yw);
    gemm_kernel<1><<<dim3(8, 64), 256, 0, stream>>>(yw, waT, b_attn, nullptr,
        flag, 8192, 1024, 1024, nullptr, x, cmodf, 2048, x1b, nullptr, nullptr);
    ln_mod_kernel<<<8192, 256, 0, stream>>>(x1b, flag, 0, cmodf, 3072, 4096,
                                            nullptr, nullptr, xmod2);
    gemm_kernel<2><<<dim3(32, 64), 256, 0, stream>>>(xmod2, wf1T, b_fc1, nullptr,
        flag, 8192, 4096, 1024, hw, nullptr, nullptr, 0, nullptr, nullptr, nullptr);
    gemm_kernel<3><<<dim3(8, 64), 256, 0, stream>>>(hw, wf2T, b_fc2, nullptr,
        flag, 8192, 1024, 4096, nullptr, nullptr, cmodf, 5120, x1b, out_xout, nullptr);

    (void)in_sizes; (void)n_in; (void)out_size; (void)ws_size;
}

// Round 8
// 640.436 us; speedup vs baseline: 1.0745x; 1.0745x over previous
//
#include <hip/hip_runtime.h>
#include <math.h>

typedef unsigned short u16;
typedef __bf16 bf16;
typedef bf16 bf16x8 __attribute__((ext_vector_type(8)));
typedef float f32x4 __attribute__((ext_vector_type(4)));

__device__ __forceinline__ float b2f(u16 u) {
    union { unsigned int i; float f; } w;
    w.i = ((unsigned int)u) << 16;
    return w.f;
}
// native RNE f32->bf16 (one v_cvt instead of 4 integer ops)
__device__ __forceinline__ u16 f2b(float f) {
    union { bf16 h; u16 u; } cv;
    cv.h = (bf16)f;
    return cv.u;
}
__device__ __forceinline__ void gload16(const void* g, void* l) {
    __builtin_amdgcn_global_load_lds(
        (const __attribute__((address_space(1))) unsigned int*)g,
        (__attribute__((address_space(3))) unsigned int*)l, 16, 0, 0);
}

// ---------------------------------------------------------- input dtype sniff
__global__ __launch_bounds__(256)
void sniff_kernel(const u16* __restrict__ w, int* __restrict__ flag) {
    __shared__ int s;
    if (threadIdx.x == 0) s = 0;
    __syncthreads();
    int big = 0;
    for (int i = threadIdx.x; i < 2048; i += 256) {
        float v = fabsf(b2f(w[2 * i]));
        if (!(v < 1e6f)) big = 1;
    }
    if (big) atomicOr(&s, 1);
    __syncthreads();
    if (threadIdx.x == 0) flag[0] = s;
}

// --------------------- 4x square weight transpose W[1024][1024]->WT (one launch)
__global__ __launch_bounds__(256)
void transpose_w4_kernel(const void* __restrict__ W0, const void* __restrict__ W1,
                         const void* __restrict__ W2, const void* __restrict__ W3,
                         const int* __restrict__ flag, u16* __restrict__ oQKV,
                         u16* __restrict__ oA) {
    __shared__ float T[32][33];
    const int z = blockIdx.z;
    const void* W = z == 0 ? W0 : (z == 1 ? W1 : (z == 2 ? W2 : W3));
    u16* out = z == 3 ? oA : (oQKV + (size_t)z * 1024 * 1024);
    const float scale = z == 0 ? (1.f / 64.f) : 1.f;
    const int tx = threadIdx.x & 31, ty = threadIdx.x >> 5;   // 32 x 8
    const int kt = blockIdx.y * 32, nt = blockIdx.x * 32;
    const int isf = flag[0];
#pragma unroll
    for (int r = 0; r < 4; ++r) {
        int k = kt + ty + r * 8;
        float v = isf ? ((const float*)W)[(size_t)k * 1024 + nt + tx]
                      : b2f(((const u16*)W)[(size_t)k * 1024 + nt + tx]);
        T[ty + r * 8][tx] = v;
    }
    __syncthreads();
#pragma unroll
    for (int r = 0; r < 4; ++r) {
        int n = nt + ty + r * 8;
        out[(size_t)n * 1024 + kt + tx] = f2b(T[tx][ty + r * 8] * scale);
    }
}

// ------------------------------------------- generic transpose (fc1/fc2)
__global__ __launch_bounds__(256)
void transpose_w_kernel(const void* __restrict__ W, const int* __restrict__ flag,
                        int K, int N, u16* __restrict__ out) {
    __shared__ float T[32][33];
    const int tx = threadIdx.x & 31, ty = threadIdx.x >> 5;
    const int kt = blockIdx.y * 32, nt = blockIdx.x * 32;
    const int isf = flag[0];
#pragma unroll
    for (int r = 0; r < 4; ++r) {
        int k = kt + ty + r * 8;
        float v = isf ? ((const float*)W)[(size_t)k * N + nt + tx]
                      : b2f(((const u16*)W)[(size_t)k * N + nt + tx]);
        T[ty + r * 8][tx] = v;
    }
    __syncthreads();
#pragma unroll
    for (int r = 0; r < 4; ++r) {
        int n = nt + ty + r * 8;
        out[(size_t)n * K + kt + tx] = f2b(T[tx][ty + r * 8]);
    }
}

// ------------------------------------------- concat qkv bias (q scaled 1/64)
__global__ __launch_bounds__(256)
void biasqkv_kernel(const void* __restrict__ bq, const void* __restrict__ bk,
                    const void* __restrict__ bv, const int* __restrict__ flag,
                    float* __restrict__ out) {
    int i = blockIdx.x * 256 + threadIdx.x;
    if (i >= 3072) return;
    const int isf = flag[0];
    const void* src = i < 1024 ? bq : (i < 2048 ? bk : bv);
    int j = i & 1023;
    float v = isf ? ((const float*)src)[j] : b2f(((const u16*)src)[j]);
    if (i < 1024) v *= (1.f / 64.f);
    out[i] = v;
}

// ---------------------------------------------------------------- silu(c)
__global__ __launch_bounds__(256)
void silu_kernel(const void* __restrict__ c, const int* __restrict__ flag,
                 float* __restrict__ cactf, float* __restrict__ out_cact) {
    int i = blockIdx.x * 256 + threadIdx.x;
    if (i < 8 * 1024) {
        float v = flag[0] ? ((const float*)c)[i] : b2f(((const u16*)c)[i]);
        float s = v / (1.f + expf(-v));
        cactf[i] = s;
        out_cact[i] = s;
    }
}

// ---------------------------- cmod stage 1: partial[ks][b][j] over 128 k's
__global__ __launch_bounds__(256)
void cmod1_kernel(const float* __restrict__ cactf, const void* __restrict__ w_mod,
                  const int* __restrict__ flag, float* __restrict__ partial) {
    __shared__ float sca[8][128];
    const int tid = threadIdx.x;
    const int ks = blockIdx.y;
    if (tid < 128) {
#pragma unroll
        for (int b = 0; b < 8; ++b) sca[b][tid] = cactf[b * 1024 + ks * 128 + tid];
    }
    __syncthreads();
    const int j = blockIdx.x * 256 + tid;
    const int isf = flag[0];
    float acc[8] = {};
    if (isf) {
        const float* wf = (const float*)w_mod + (size_t)(ks * 128) * 6144 + j;
        for (int k = 0; k < 128; ++k) {
            float wv = wf[(size_t)k * 6144];
#pragma unroll
            for (int b = 0; b < 8; ++b) acc[b] = fmaf(sca[b][k], wv, acc[b]);
        }
    } else {
        const u16* wb = (const u16*)w_mod + (size_t)(ks * 128) * 6144 + j;
        for (int k = 0; k < 128; ++k) {
            float wv = b2f(wb[(size_t)k * 6144]);
#pragma unroll
            for (int b = 0; b < 8; ++b) acc[b] = fmaf(sca[b][k], wv, acc[b]);
        }
    }
#pragma unroll
    for (int b = 0; b < 8; ++b) partial[(ks * 8 + b) * 6144 + j] = acc[b];
}

// ---------------------------- cmod stage 2: reduce + bias + outputs
__global__ __launch_bounds__(256)
void cmod2_kernel(const float* __restrict__ partial, const void* __restrict__ b_mod,
                  const int* __restrict__ flag, float* __restrict__ cmodf,
                  float* __restrict__ out_cmod, float* __restrict__ out_shift,
                  float* __restrict__ out_scale) {
    const int j = blockIdx.x * 256 + threadIdx.x;
    const int isf = flag[0];
    float bm = isf ? ((const float*)b_mod)[j] : b2f(((const u16*)b_mod)[j]);
#pragma unroll
    for (int b = 0; b < 8; ++b) {
        float acc = bm;
#pragma unroll
        for (int ks = 0; ks < 8; ++ks) acc += partial[(ks * 8 + b) * 6144 + j];
        cmodf[b * 6144 + j] = acc;
        out_cmod[b * 6144 + j] = acc;
        if (j < 1024) out_shift[b * 1024 + j] = acc;
        else if (j < 2048) out_scale[b * 1024 + (j - 1024)] = acc;
    }
}

// -------------------------------------------------- LayerNorm + modulate
__global__ __launch_bounds__(256)
void ln_mod_kernel(const void* __restrict__ xin, const int* __restrict__ flag,
                   int dtype, const float* __restrict__ cmodf,
                   int shift_off, int scale_off, float* __restrict__ out_norm,
                   float* __restrict__ out_mod, u16* __restrict__ ws_mod) {
    const int row = blockIdx.x;
    const int tid = threadIdx.x;
    const int bidx = row >> 10;
    const int isf = (dtype == 2) ? flag[0] : dtype;
    const size_t base = (size_t)row * 1024 + tid * 4;
    float v[4];
    if (isf) {
        float4 f = *reinterpret_cast<const float4*>((const float*)xin + base);
        v[0] = f.x; v[1] = f.y; v[2] = f.z; v[3] = f.w;
    } else {
        ushort4 u = *reinterpret_cast<const ushort4*>((const u16*)xin + base);
        v[0] = b2f(u.x); v[1] = b2f(u.y); v[2] = b2f(u.z); v[3] = b2f(u.w);
    }
    float s = v[0] + v[1] + v[2] + v[3];
#pragma unroll
    for (int o = 32; o; o >>= 1) s += __shfl_xor(s, o, 64);
    __shared__ float red1[4], red2[4];
    const int lane = tid & 63, wv = tid >> 6;
    if (lane == 0) red1[wv] = s;
    __syncthreads();
    float mean = (red1[0] + red1[1] + red1[2] + red1[3]) * 0.0009765625f;
    float d0 = v[0] - mean, d1 = v[1] - mean, d2 = v[2] - mean, d3 = v[3] - mean;
    float sq = d0 * d0 + d1 * d1 + d2 * d2 + d3 * d3;
#pragma unroll
    for (int o = 32; o; o >>= 1) sq += __shfl_xor(sq, o, 64);
    if (lane == 0) red2[wv] = sq;
    __syncthreads();
    float var = (red2[0] + red2[1] + red2[2] + red2[3]) * 0.0009765625f;
    float rs = rsqrtf(var + 1e-6f);
    float xn[4] = {d0 * rs, d1 * rs, d2 * rs, d3 * rs};
    const int d = tid * 4;
    const float* cb = cmodf + bidx * 6144;
    float4 fn = {xn[0], xn[1], xn[2], xn[3]};
    float4 fm;
    fm.x = xn[0] * (1.f + cb[scale_off + d + 0]) + cb[shift_off + d + 0];
    fm.y = xn[1] * (1.f + cb[scale_off + d + 1]) + cb[shift_off + d + 1];
    fm.z = xn[2] * (1.f + cb[scale_off + d + 2]) + cb[shift_off + d + 2];
    fm.w = xn[3] * (1.f + cb[scale_off + d + 3]) + cb[shift_off + d + 3];
    if (out_norm) *reinterpret_cast<float4*>(out_norm + base) = fn;
    if (out_mod)  *reinterpret_cast<float4*>(out_mod + base)  = fm;
    if (ws_mod) {
        ushort4 um = {f2b(fm.x), f2b(fm.y), f2b(fm.z), f2b(fm.w)};
        *reinterpret_cast<ushort4*>(ws_mod + base) = um;
    }
}

// ------------------------------------------------------------ MFMA GEMM (m97)
// MODE 0: qkv: Q,K parts -> Cb; V part -> VTg[b][h][dh][s] (transposed store)
// MODE 1: x1b = bf16(f(Xres) + gate_msa * C)
// MODE 2: Cb = bf16(gelu_exact(C))
// MODE 3: outf = f(x1b) + gate_mlp * C
// v3: XCD-aware chunked block swizzle (T1).
// v4: BK=64 (halves barrier/drain events per K-element).
// v5: T2 XOR swizzle, both-sides (rule #21).
template <int MODE>
__global__ __launch_bounds__(256, 2)
void gemm_kernel(const u16* __restrict__ A, const u16* __restrict__ BT,
                 const void* __restrict__ bias, const float* __restrict__ bias32,
                 const int* __restrict__ flag, int M, int N, int K,
                 u16* __restrict__ Cb, const void* __restrict__ Xres,
                 const float* __restrict__ cmodf, int gate_off,
                 u16* __restrict__ x1b, float* __restrict__ outf,
                 u16* __restrict__ VTg) {
    __shared__ __align__(16) u16 Al[128 * 64];
    __shared__ __align__(16) u16 Bl[128 * 64];
    const int tid = threadIdx.x, lane = tid & 63, w = tid >> 6;
    const int nwg = gridDim.x * gridDim.y;
    const int bid = blockIdx.y * gridDim.x + blockIdx.x;
    const int swz = (bid & 7) * (nwg >> 3) + (bid >> 3);
    const int m0 = (swz / gridDim.x) * 128, n0 = (swz % gridDim.x) * 128;
    const int wr = (w & 1) * 64, wc = (w >> 1) * 64;
    const int l15 = lane & 15, quad = lane >> 4;
    const int srow = lane >> 3;                              // 0..7 within chunk
    const int sslot = ((lane & 7) ^ srow) * 8;               // pre-swizzled src slot (u16)
    const int m7 = l15 & 7;
    const int s0 = (quad ^ m7) * 8;                          // kk=0 read slot (u16)
    const int s1 = ((4 + quad) ^ m7) * 8;                    // kk=1 read slot (u16)
    f32x4 acc[4][4] = {};
    for (int k0 = 0; k0 < K; k0 += 64) {
        __syncthreads();
#pragma unroll
        for (int c = 0; c < 4; ++c) {
            const int chunk = w * 4 + c;              // 16 chunks of 8 rows
            const int row = chunk * 8 + srow;
            gload16(A + (size_t)(m0 + row) * K + k0 + sslot, &Al[chunk * 512]);
            gload16(BT + (size_t)(n0 + row) * K + k0 + sslot, &Bl[chunk * 512]);
        }
        __syncthreads();
#pragma unroll
        for (int kk = 0; kk < 2; ++kk) {
            const int sk = kk ? s1 : s0;
            bf16x8 afr[4], bfr[4];
#pragma unroll
            for (int i = 0; i < 4; ++i)
                afr[i] = *(const bf16x8*)&Al[(wr + i * 16 + l15) * 64 + sk];
#pragma unroll
            for (int j = 0; j < 4; ++j)
                bfr[j] = *(const bf16x8*)&Bl[(wc + j * 16 + l15) * 64 + sk];
#pragma unroll
            for (int i = 0; i < 4; ++i)
#pragma unroll
                for (int j = 0; j < 4; ++j)
                    acc[i][j] = __builtin_amdgcn_mfma_f32_16x16x32_bf16(
                        afr[i], bfr[j], acc[i][j], 0, 0, 0);
        }
    }
    const int isf = flag[0];
    const int rbase = (lane >> 4) << 2;
#pragma unroll
    for (int i = 0; i < 4; ++i) {
#pragma unroll
        for (int j = 0; j < 4; ++j) {
            const int colbase = n0 + wc + j * 16;
            const int col = colbase + l15;
            float bv;
            if (MODE == 0) bv = bias32[col];
            else bv = isf ? ((const float*)bias)[col] : b2f(((const u16*)bias)[col]);
#pragma unroll
            for (int r = 0; r < 4; ++r) {
                const int m = m0 + wr + i * 16 + rbase + r;
                float t = acc[i][j][r] + bv;
                const size_t idx = (size_t)m * N + col;
                if (MODE == 0) {
                    if (colbase >= 2048) {   // V part: store transposed
                        const int hh = (col - 2048) >> 6, dh = (col - 2048) & 63;
                        const int bb = m >> 10, ss = m & 1023;
                        VTg[(((size_t)bb * 16 + hh) * 64 + dh) * 1024 + ss] = f2b(t);
                    } else {
                        Cb[idx] = f2b(t);
                    }
                } else if (MODE == 1) {
                    const int bb = m >> 10;
                    float g = cmodf[bb * 6144 + gate_off + col];
                    float xr = isf ? ((const float*)Xres)[idx]
                                   : b2f(((const u16*)Xres)[idx]);
                    x1b[idx] = f2b(xr + g * t);
                } else if (MODE == 2) {
                    float gl = 0.5f * t * (1.f + erff(t * 0.70710678118654752f));
                    Cb[idx] = f2b(gl);
                } else {
                    const int bb = m >> 10;
                    float g = cmodf[bb * 6144 + gate_off + col];
                    outf[idx] = b2f(x1b[idx]) + g * t;
                }
            }
        }
    }
}

// --------------------------------------------- fused flash attention (64-row Q)
// QKV[8192][3072] (Q+0, K+1024; V region unused), VT[b][h][64][1024].
// v2: qS dropped (Q direct to regs); async-STAGE split (T14); setprio (T5).
// v3: XCD-aware chunked swizzle (T1) — each XCD owns one batch b.
// v7: KVBLK=128, no defer-max (v6 regressed: VGPR 80->96, occ 29->21);
//     DROP barrier #3 (P-store -> pa-load): pS stripe [w*16, w*16+16) is
//     wave-private for both writes and reads — only intra-wave LDS ordering
//     needed (compiler lgkmcnt). Also lets softmax(VALU) of one wave overlap
//     PV(MFMA) of another => setprio has something to arbitrate.
//     Prefetch uses running pointers (no per-tile 64-bit muls).
__global__ __launch_bounds__(256, 2)
void attn_kernel(const u16* __restrict__ QKV, const u16* __restrict__ VT,
                 u16* __restrict__ Y) {
    __shared__ __align__(16) u16 kS[128 * 72];
    __shared__ __align__(16) u16 vS[64 * 132];   // [dh][key]
    __shared__ __align__(16) u16 pS[64 * 132];   // [q][key] — wave-private stripes
    const int tid = threadIdx.x, lane = tid & 63, w = tid >> 6;
    const int l15 = lane & 15, quad = lane >> 4;
    const int kq = quad * 8, rbase = quad * 4;
    // swizzle: nwg = 16*16*8 = 2048; chunk 256 per XCD = exactly one batch b
    const int bid = blockIdx.x + 16 * (blockIdx.y + 16 * blockIdx.z);
    const int swz = (bid & 7) * 256 + (bid >> 3);
    const int qt = swz & 15, h = (swz >> 4) & 15, b = swz >> 8;
    const int s0 = qt * 64;
    const size_t rowbase = (size_t)b * 1024;
    const int hq = h * 64, hk = 1024 + h * 64;
    const u16* vtg = VT + ((size_t)b * 16 + h) * 64 * 1024;
    // Q fragments straight from global (one-time, 32B/thread)
    bf16x8 qa[2];
#pragma unroll
    for (int ks = 0; ks < 2; ++ks)
        qa[ks] = *(const bf16x8*)(QKV + (rowbase + s0 + w * 16 + l15) * 3072 +
                                  hq + ks * 32 + kq);
    // per-thread fixed staging offsets; running pointers advance per tile
    const int idx0 = tid, idx1 = 256 + tid, idx2 = 512 + tid, idx3 = 768 + tid;
    const int koff[4] = {(idx0 >> 3) * 3072 + (idx0 & 7) * 8,
                         (idx1 >> 3) * 3072 + (idx1 & 7) * 8,
                         (idx2 >> 3) * 3072 + (idx2 & 7) * 8,
                         (idx3 >> 3) * 3072 + (idx3 & 7) * 8};
    const int voff[4] = {(idx0 >> 4) * 1024 + (idx0 & 15) * 8,
                         (idx1 >> 4) * 1024 + (idx1 & 15) * 8,
                         (idx2 >> 4) * 1024 + (idx2 & 15) * 8,
                         (idx3 >> 4) * 1024 + (idx3 & 15) * 8};
    const int klds[4] = {(idx0 >> 3) * 72 + (idx0 & 7) * 8,
                         (idx1 >> 3) * 72 + (idx1 & 7) * 8,
                         (idx2 >> 3) * 72 + (idx2 & 7) * 8,
                         (idx3 >> 3) * 72 + (idx3 & 7) * 8};
    const int vlds[4] = {(idx0 >> 4) * 132 + (idx0 & 15) * 8,
                         (idx1 >> 4) * 132 + (idx1 & 15) * 8,
                         (idx2 >> 4) * 132 + (idx2 & 15) * 8,
                         (idx3 >> 4) * 132 + (idx3 & 15) * 8};
    const u16* kcur = QKV + rowbase * 3072 + hk;
    const u16* vcur = vtg;
    // prefetch K/V tile 0 into registers
    bf16x8 kreg[4], vreg[4];
#pragma unroll
    for (int it = 0; it < 4; ++it) {
        kreg[it] = *(const bf16x8*)(kcur + koff[it]);
        vreg[it] = *(const bf16x8*)(vcur + voff[it]);
    }
    f32x4 accO[4] = {};
    float m_i[4], l_i[4];
#pragma unroll
    for (int r = 0; r < 4; ++r) { m_i[r] = -3e38f; l_i[r] = 0.f; }
    for (int kt = 0; kt < 8; ++kt) {
        __syncthreads();                     // b1: prev tile fully consumed
        // write prefetched tile regs -> LDS
#pragma unroll
        for (int it = 0; it < 4; ++it) {
            *(bf16x8*)&kS[klds[it]] = kreg[it];
            *(bf16x8*)&vS[vlds[it]] = vreg[it];
        }
        // issue next tile's global loads now; latency hides under compute below
        if (kt < 7) {
            kcur += 128 * 3072;
            vcur += 128;
#pragma unroll
            for (int it = 0; it < 4; ++it) {
                kreg[it] = *(const bf16x8*)(kcur + koff[it]);
                vreg[it] = *(const bf16x8*)(vcur + voff[it]);
            }
        }
        __syncthreads();                     // b2: staging visible
        // S = Q K^T
        f32x4 s[8];
        __builtin_amdgcn_s_setprio(1);
#pragma unroll
        for (int nt = 0; nt < 8; ++nt) {
            f32x4 a = {};
#pragma unroll
            for (int ks = 0; ks < 2; ++ks) {
                bf16x8 kb = *(const bf16x8*)&kS[(nt * 16 + l15) * 72 + ks * 32 + kq];
                a = __builtin_amdgcn_mfma_f32_16x16x32_bf16(qa[ks], kb, a, 0, 0, 0);
            }
            s[nt] = a;
        }
        __builtin_amdgcn_s_setprio(0);
        float alpha[4];
#pragma unroll
        for (int r = 0; r < 4; ++r) {
            float mx = fmaxf(fmaxf(fmaxf(s[0][r], s[1][r]), fmaxf(s[2][r], s[3][r])),
                             fmaxf(fmaxf(s[4][r], s[5][r]), fmaxf(s[6][r], s[7][r])));
            mx = fmaxf(mx, __shfl_xor(mx, 1));
            mx = fmaxf(mx, __shfl_xor(mx, 2));
            mx = fmaxf(mx, __shfl_xor(mx, 4));
            mx = fmaxf(mx, __shfl_xor(mx, 8));
            float mn = fmaxf(m_i[r], mx);
            alpha[r] = __expf(m_i[r] - mn);
            m_i[r] = mn;
            float rs = 0.f;
#pragma unroll
            for (int nt = 0; nt < 8; ++nt) {
                float p = __expf(s[nt][r] - mn);
                s[nt][r] = p;
                rs += p;
            }
            rs += __shfl_xor(rs, 1);
            rs += __shfl_xor(rs, 2);
            rs += __shfl_xor(rs, 4);
            rs += __shfl_xor(rs, 8);
            l_i[r] = l_i[r] * alpha[r] + rs;
        }
        // P -> LDS (wave-private stripe; no cross-wave barrier needed)
#pragma unroll
        for (int nt = 0; nt < 8; ++nt)
#pragma unroll
            for (int r = 0; r < 4; ++r)
                pS[(w * 16 + rbase + r) * 132 + nt * 16 + l15] = f2b(s[nt][r]);
#pragma unroll
        for (int dt = 0; dt < 4; ++dt)
#pragma unroll
            for (int r = 0; r < 4; ++r) accO[dt][r] *= alpha[r];
        bf16x8 pa[4];
#pragma unroll
        for (int ks = 0; ks < 4; ++ks)
            pa[ks] = *(const bf16x8*)&pS[(w * 16 + l15) * 132 + ks * 32 + kq];
        __builtin_amdgcn_s_setprio(1);
#pragma unroll
        for (int dt = 0; dt < 4; ++dt) {
#pragma unroll
            for (int ks = 0; ks < 4; ++ks) {
                bf16x8 vb = *(const bf16x8*)&vS[(dt * 16 + l15) * 132 + ks * 32 + kq];
                accO[dt] = __builtin_amdgcn_mfma_f32_16x16x32_bf16(pa[ks], vb, accO[dt], 0, 0, 0);
            }
        }
        __builtin_amdgcn_s_setprio(0);
    }
#pragma unroll
    for (int dt = 0; dt < 4; ++dt)
#pragma unroll
        for (int r = 0; r < 4; ++r) {
            float o = accO[dt][r] / l_i[r];
            Y[(rowbase + s0 + w * 16 + rbase + r) * 1024 + h * 64 + dt * 16 + l15] = f2b(o);
        }
}

// ----------------------------------------------------------------- launch
extern "C" void kernel_launch(void* const* d_in, const int* in_sizes, int n_in,
                              void* d_out, int out_size, void* d_ws, size_t ws_size,
                              hipStream_t stream) {
    const void* x      = d_in[0];
    const void* c      = d_in[1];
    const void* w_mod  = d_in[2];
    const void* b_mod  = d_in[3];
    const void* w_q    = d_in[4];
    const void* b_q    = d_in[5];
    const void* w_k    = d_in[6];
    const void* b_k    = d_in[7];
    const void* w_v    = d_in[8];
    const void* b_v    = d_in[9];
    const void* w_attn = d_in[10];
    const void* b_attn = d_in[11];
    const void* w_fc1  = d_in[12];
    const void* b_fc1  = d_in[13];
    const void* w_fc2  = d_in[14];
    const void* b_fc2  = d_in[15];

    float* out = (float*)d_out;
    float* out_xout  = out;
    float* out_norm  = out + 8388608;
    float* out_mod   = out + 16777216;
    float* out_shift = out + 25165824;
    float* out_scale = out + 25174016;
    float* out_cmod  = out + 25182208;
    float* out_cact  = out + 25231360;

    char* ws = (char*)d_ws;
    float* cactf   = (float*)(ws + 0);
    float* cmodf   = (float*)(ws + 32768);
    int*   flag    = (int*)(ws + 229376);
    float* bqkv    = (float*)(ws + 230400);
    float* partial = (float*)(ws + 262144);      // 1.57 MB
    u16* wqkvT = (u16*)(ws + 2097152);           // 6 MB
    u16* waT   = (u16*)(ws + 8388608);           // 2 MB
    u16* wf1T  = (u16*)(ws + 10485760);          // 8 MB
    u16* wf2T  = (u16*)(ws + 18874368);          // 8 MB  (end 27262976)
    u16* xmod  = (u16*)(ws + 27262976);          // 16 MB
    u16* yw    = xmod;                           // alias: xmod dead after qkv GEMM
    u16* qkv   = (u16*)(ws + 44040192);          // 48 MB (V third unused)
    u16* xmod2 = qkv;                            // alias: qkv dead after attn
    u16* vtg   = (u16*)(ws + 94371840);          // 16 MB
    u16* hw    = (u16*)(ws + 60817408);          // 64 MB, overlays dead qkv-tail+vtg
    u16* x1b   = (u16*)(ws + 127926272);         // 16 MB (end ~138 MiB)

    sniff_kernel<<<1, 256, 0, stream>>>((const u16*)w_q, flag);
    transpose_w4_kernel<<<dim3(32, 32, 4), 256, 0, stream>>>(w_q, w_k, w_v, w_attn,
        flag, wqkvT, waT);
    transpose_w_kernel<<<dim3(128, 32), 256, 0, stream>>>(w_fc1, flag, 1024, 4096, wf1T);
    transpose_w_kernel<<<dim3(32, 128), 256, 0, stream>>>(w_fc2, flag, 4096, 1024, wf2T);
    biasqkv_kernel<<<12, 256, 0, stream>>>(b_q, b_k, b_v, flag, bqkv);

    silu_kernel<<<32, 256, 0, stream>>>(c, flag, cactf, out_cact);
    cmod1_kernel<<<dim3(24, 8), 256, 0, stream>>>(cactf, w_mod, flag, partial);
    cmod2_kernel<<<24, 256, 0, stream>>>(partial, b_mod, flag, cmodf,
                                         out_cmod, out_shift, out_scale);
    ln_mod_kernel<<<8192, 256, 0, stream>>>(x, flag, 2, cmodf, 0, 1024,
                                            out_norm, out_mod, xmod);
    gemm_kernel<0><<<dim3(24, 64), 256, 0, stream>>>(xmod, wqkvT, nullptr, bqkv,
        flag, 8192, 3072, 1024, qkv, nullptr, nullptr, 0, nullptr, nullptr, vtg);
    attn_kernel<<<dim3(16, 16, 8), 256, 0, stream>>>(qkv, vtg, yw);
    gemm_kernel<1><<<dim3(8, 64), 256, 0, stream>>>(yw, waT, b_attn, nullptr,
        flag, 8192, 1024, 1024, nullptr, x, cmodf, 2048, x1b, nullptr, nullptr);
    ln_mod_kernel<<<8192, 256, 0, stream>>>(x1b, flag, 0, cmodf, 3072, 4096,
                                            nullptr, nullptr, xmod2);
    gemm_kernel<2><<<dim3(32, 64), 256, 0, stream>>>(xmod2, wf1T, b_fc1, nullptr,
        flag, 8192, 4096, 1024, hw, nullptr, nullptr, 0, nullptr, nullptr, nullptr);
    gemm_kernel<3><<<dim3(8, 64), 256, 0, stream>>>(hw, wf2T, b_fc2, nullptr,
        flag, 8192, 1024, 4096, nullptr, nullptr, cmodf, 5120, x1b, out_xout, nullptr);

    (void)in_sizes; (void)n_in; (void)out_size; (void)ws_size;
}